// Round 4
// baseline (227.614 us; speedup 1.0000x reference)
//
#include <hip/hip_runtime.h>

#define NA 4096
#define HS 128
#define PSTR 72    // attn P-buffer row stride (bf16 elems)
#define CSTR 136   // proj/reduce LDS row stride (bf16 elems)

typedef unsigned short u16;
typedef unsigned long long u64;
using bf16x8  = __attribute__((ext_vector_type(8))) short;
using f32x4   = __attribute__((ext_vector_type(4))) float;
using ushort8 = __attribute__((ext_vector_type(8))) unsigned short;

// 1/sqrt(dk)=0.25 * log2(e) * 0.5 (K-dim duplication in the 16x16x32 MFMA)
#define QSCALE 0.18033688011112042f

static __device__ __forceinline__ u16 f2bf(float f) {
    unsigned u = __builtin_bit_cast(unsigned, f);
    u += 0x7FFFu + ((u >> 16) & 1u);
    return (u16)(u >> 16);
}

// ---------------------------------------------------------------------------
// Kernel 0: weights -> bf16. Wbuf[mat][j][k], mat: 0=Q(x QSCALE), 1=K, 2=V,
// 3=O. bb[mat][j] f32 biases (bq pre-scaled).
// ---------------------------------------------------------------------------
__global__ __launch_bounds__(256) void cvt_w(
    const float* __restrict__ Wq, const float* __restrict__ Wk,
    const float* __restrict__ Wv, const float* __restrict__ Wo,
    const float* __restrict__ bq, const float* __restrict__ bk,
    const float* __restrict__ bv,
    u16* __restrict__ Wbuf, float* __restrict__ bb)
{
    const int gid = blockIdx.x * 256 + threadIdx.x;   // 16384 threads
    const int e = gid * 4;
    const int mat = e >> 14, off = e & 16383;
    const float* src = (mat == 0) ? Wq : (mat == 1) ? Wk : (mat == 2) ? Wv : Wo;
    const float s = (mat == 0) ? QSCALE : 1.0f;
    float4 v = *(const float4*)(src + off);
    ushort4 o;
    o.x = f2bf(v.x * s); o.y = f2bf(v.y * s);
    o.z = f2bf(v.z * s); o.w = f2bf(v.w * s);
    *(ushort4*)(Wbuf + e) = o;
    if (gid < 128)      bb[gid] = bq[gid] * QSCALE;
    else if (gid < 256) bb[gid] = bk[gid - 128];
    else if (gid < 384) bb[gid] = bv[gid - 256];
}

// ---------------------------------------------------------------------------
// Kernel 1: Q/K/V projections via MFMA. Block = 256 thr (4 waves) = 32 rows.
// X staged coalesced into LDS (f32->bf16); wave (rw, colgroup) does 16 rows x
// 64 cols; C staged in LDS, stored coalesced. Vt transposed [dim][row].
// ---------------------------------------------------------------------------
__global__ __launch_bounds__(256) void proj_mfma(
    const float* __restrict__ Xq, const float* __restrict__ Xk, const float* __restrict__ Xv,
    const u16* __restrict__ Wbuf, const float* __restrict__ bb,
    u16* __restrict__ Qb, u16* __restrict__ Kb, u16* __restrict__ Vt)
{
    const int mat = blockIdx.y;
    const float* X = (mat == 0) ? Xq : (mat == 1) ? Xk : Xv;
    const u16* Wm = Wbuf + mat * 16384;
    const float* bm = bb + mat * 128;
    const int r0b = blockIdx.x * 32;

    __shared__ __align__(16) u16 Xs[32 * CSTR];
    __shared__ __align__(16) u16 Cs[32 * CSTR];

    const int t = threadIdx.x;

    // stage X coalesced: thread -> row t>>3, 16 cols at (t&7)*16
    {
        const int r = t >> 3, cb = (t & 7) * 16;
        const float* Xr = X + (size_t)(r0b + r) * HS + cb;
#pragma unroll
        for (int seg = 0; seg < 4; ++seg) {
            float4 f = *(const float4*)(Xr + seg * 4);
            ushort4 u;
            u.x = f2bf(f.x); u.y = f2bf(f.y); u.z = f2bf(f.z); u.w = f2bf(f.w);
            *(ushort4*)(Xs + r * CSTR + cb + seg * 4) = u;
        }
    }
    __syncthreads();

    const int wv = t >> 6, lane = t & 63;
    const int c = lane & 15, q = lane >> 4;
    const int rw = (wv & 1) * 16;        // wave row offset in block
    const int j0b = (wv >> 1) * 4;       // wave col group (4 j0 of 16 cols)

    bf16x8 af[4];
#pragma unroll
    for (int kk = 0; kk < 4; ++kk)
        af[kk] = *(const bf16x8*)(Xs + (rw + c) * CSTR + kk * 32 + q * 8);

    const f32x4 zero = {0.f, 0.f, 0.f, 0.f};
#pragma unroll
    for (int jj = 0; jj < 4; ++jj) {
        const int j0 = j0b + jj;
        f32x4 acc = zero;
#pragma unroll
        for (int kk = 0; kk < 4; ++kk) {
            bf16x8 bf = *(const bf16x8*)(Wm + (size_t)(j0 * 16 + c) * HS + kk * 32 + q * 8);
            acc = __builtin_amdgcn_mfma_f32_16x16x32_bf16(af[kk], bf, acc, 0, 0, 0);
        }
        const float bias = bm[j0 * 16 + c];
#pragma unroll
        for (int r = 0; r < 4; ++r)
            Cs[(rw + 4 * q + r) * CSTR + j0 * 16 + c] = f2bf(acc[r] + bias);
    }
    __syncthreads();

    if (mat < 2) {
        u16* dst = (mat == 0) ? Qb : Kb;
        const int r = t >> 3, cb = (t & 7) * 16;
        *(bf16x8*)(dst + (size_t)(r0b + r) * HS + cb)     = *(const bf16x8*)(Cs + r * CSTR + cb);
        *(bf16x8*)(dst + (size_t)(r0b + r) * HS + cb + 8) = *(const bf16x8*)(Cs + r * CSTR + cb + 8);
    } else {
        const int j = t & 127, half = t >> 7;   // rows half*16 .. +15
        ushort8 v0, v1;
#pragma unroll
        for (int ii = 0; ii < 8; ++ii) v0[ii] = Cs[(half * 16 + ii) * CSTR + j];
#pragma unroll
        for (int ii = 0; ii < 8; ++ii) v1[ii] = Cs[(half * 16 + 8 + ii) * CSTR + j];
        *(ushort8*)(Vt + (size_t)j * NA + r0b + half * 16)     = v0;
        *(ushort8*)(Vt + (size_t)j * NA + r0b + half * 16 + 8) = v1;
    }
}

// ---------------------------------------------------------------------------
// Kernel 2: attention partials. Grid (256 tiles, 4 key-splits), 512 thr =
// 8 waves, wave = one head. Mask slice (16 rows x 1024 cols) is ballot-packed
// cooperatively into LDS bits (coalesced 256B reads), then the hot loop uses
// one broadcast ds_read_b64 per iter. S^T = K*Q^T so each lane holds 4
// consecutive keys -> P-transpose via 4x ds_write_b64. p = 2^S (no max
// subtraction; |S|<~15 in log2 units), so partials add across splits.
// part[tile][split][head][272] = { O 16x16 f32, l 16 f32 }.
// ---------------------------------------------------------------------------
__global__ __launch_bounds__(512, 8) void attn(
    const int* __restrict__ mask,
    const u16* __restrict__ Qb, const u16* __restrict__ Kb, const u16* __restrict__ Vt,
    float* __restrict__ part)
{
    __shared__ __align__(16) u16 Pbuf[8 * 16 * PSTR];
    __shared__ __align__(8)  u64 Mwp[16 * 17];   // [query][word], padded stride

    const int t = threadIdx.x;
    const int h = t >> 6;        // wave = head
    const int lane = t & 63;
    const int c = lane & 15;
    const int q = lane >> 4;
    const int tile = blockIdx.x, split = blockIdx.y;
    const int i0 = tile * 16;
    const int kt0 = split * 1024;

    // --- ballot-pack mask bits: 256 u64 words, wave h does words h*32..+31
#pragma unroll 4
    for (int rr = 0; rr < 32; ++rr) {
        const int idx = h * 32 + rr;
        const int row = idx >> 4, wc = idx & 15;
        const int v = mask[(size_t)(i0 + row) * NA + kt0 + wc * 64 + lane];
        u64 b = __ballot(v != 0);
        if (lane == 0) Mwp[row * 17 + wc] = b;
    }

    // Q B-fragment (K-halves duplicated; x2 folded into QSCALE)
    const bf16x8 qf = *(const bf16x8*)(Qb + (size_t)(i0 + c) * HS + h * 16 + (q & 1) * 8);

    __syncthreads();

    const f32x4 zero = {0.f, 0.f, 0.f, 0.f};
    f32x4 Oacc = zero;
    float lsum = 0.f;
    u16* Pw = Pbuf + h * 16 * PSTR;

#pragma unroll 1
    for (int it = 0; it < 16; ++it) {
        const int kt = kt0 + it * 64;

        // S^T = K Q^T: lane (c,q) reg r = S[query i0+c][key kt+16*t4+4q+r]
        f32x4 ST[4];
#pragma unroll
        for (int t4 = 0; t4 < 4; ++t4) {
            bf16x8 kf = *(const bf16x8*)(Kb + (size_t)(kt + t4 * 16 + c) * HS + h * 16 + (q & 1) * 8);
            ST[t4] = __builtin_amdgcn_mfma_f32_16x16x32_bf16(kf, qf, zero, 0, 0, 0);
        }
        // V B-fragments for this iter (issue early, before the LDS drain)
        bf16x8 vf0 = *(const bf16x8*)(Vt + (size_t)(h * 16 + c) * NA + kt + q * 8);
        bf16x8 vf1 = *(const bf16x8*)(Vt + (size_t)(h * 16 + c) * NA + kt + 32 + q * 8);

        // mask bits for this lane's query, shifted so bit(16*t4+r) = key 16*t4+4q+r
        u64 w = Mwp[c * 17 + it] >> (4 * q);
        unsigned mlo = (unsigned)w, mhi = (unsigned)(w >> 32);

#pragma unroll
        for (int t4 = 0; t4 < 4; ++t4) {
            const unsigned mw = (t4 < 2) ? mlo : mhi;
            const int sh = (t4 & 1) * 16;
            float p0 = ((mw >> (sh + 0)) & 1) ? __builtin_amdgcn_exp2f(ST[t4][0]) : 0.f;
            float p1 = ((mw >> (sh + 1)) & 1) ? __builtin_amdgcn_exp2f(ST[t4][1]) : 0.f;
            float p2 = ((mw >> (sh + 2)) & 1) ? __builtin_amdgcn_exp2f(ST[t4][2]) : 0.f;
            float p3 = ((mw >> (sh + 3)) & 1) ? __builtin_amdgcn_exp2f(ST[t4][3]) : 0.f;
            lsum += (p0 + p1) + (p2 + p3);
            // pack 4 consecutive keys (bf16, round-half-up) -> one b64 write
            unsigned lo = ((__builtin_bit_cast(unsigned, p0) + 0x8000u) >> 16)
                        | ((__builtin_bit_cast(unsigned, p1) + 0x8000u) & 0xFFFF0000u);
            unsigned hi = ((__builtin_bit_cast(unsigned, p2) + 0x8000u) >> 16)
                        | ((__builtin_bit_cast(unsigned, p3) + 0x8000u) & 0xFFFF0000u);
            *(uint2*)(Pw + c * PSTR + t4 * 16 + 4 * q) = make_uint2(lo, hi);
        }
        __asm__ volatile("" ::: "memory");
        __builtin_amdgcn_s_waitcnt(0xC07F);  // per-wave LDS drain
        __asm__ volatile("" ::: "memory");

        // O += P @ V
        bf16x8 pf0 = *(const bf16x8*)(Pw + c * PSTR + q * 8);
        bf16x8 pf1 = *(const bf16x8*)(Pw + c * PSTR + 32 + q * 8);
        Oacc = __builtin_amdgcn_mfma_f32_16x16x32_bf16(pf0, vf0, Oacc, 0, 0, 0);
        Oacc = __builtin_amdgcn_mfma_f32_16x16x32_bf16(pf1, vf1, Oacc, 0, 0, 0);
    }

    // l[query c]: sum the 4 q-lanes
    lsum += __shfl_xor(lsum, 16, 64);
    lsum += __shfl_xor(lsum, 32, 64);

    float* base = part + (size_t)((tile * 4 + split) * 8 + h) * 272;
#pragma unroll
    for (int r = 0; r < 4; ++r)
        base[(4 * q + r) * 16 + c] = Oacc[r];
    if (q == 0) base[256 + c] = lsum;
}

// ---------------------------------------------------------------------------
// Kernel 3: combine 4 split partials, normalize, output projection via MFMA.
// ---------------------------------------------------------------------------
__global__ __launch_bounds__(256) void reduce_out(
    const float* __restrict__ part, const u16* __restrict__ Wbuf,
    float* __restrict__ out)
{
    __shared__ __align__(16) u16 xs[16 * CSTR];

    const int t = threadIdx.x;
    const int tile = blockIdx.x;
    const int i0 = tile * 16;
    const float* Pt = part + (size_t)tile * 4 * 8 * 272;

    {
        const int i = t >> 4, d = t & 15;
#pragma unroll
        for (int h = 0; h < 8; ++h) {
            float os = 0.f, ls = 0.f;
#pragma unroll
            for (int s = 0; s < 4; ++s) {
                const float* b = Pt + (size_t)(s * 8 + h) * 272;
                os += b[i * 16 + d];
                ls += b[256 + i];
            }
            xs[i * CSTR + h * 16 + d] = f2bf(os / ls);
        }
    }
    __syncthreads();

    const int wv = t >> 6, lane = t & 63;
    const int c = lane & 15, q = lane >> 4;
    const u16* WoB = Wbuf + 3 * 16384;

    bf16x8 af[4];
#pragma unroll
    for (int kk = 0; kk < 4; ++kk)
        af[kk] = *(const bf16x8*)(xs + c * CSTR + kk * 32 + q * 8);

    const f32x4 zero = {0.f, 0.f, 0.f, 0.f};
#pragma unroll
    for (int jj = 0; jj < 2; ++jj) {
        const int j0 = wv * 2 + jj;
        f32x4 acc = zero;
#pragma unroll
        for (int kk = 0; kk < 4; ++kk) {
            bf16x8 bf = *(const bf16x8*)(WoB + (size_t)(j0 * 16 + c) * HS + kk * 32 + q * 8);
            acc = __builtin_amdgcn_mfma_f32_16x16x32_bf16(af[kk], bf, acc, 0, 0, 0);
        }
#pragma unroll
        for (int r = 0; r < 4; ++r)
            out[(size_t)(i0 + 4 * q + r) * HS + j0 * 16 + c] = acc[r];
    }
}

extern "C" void kernel_launch(void* const* d_in, const int* in_sizes, int n_in,
                              void* d_out, int out_size, void* d_ws, size_t ws_size,
                              hipStream_t stream) {
    const float* query = (const float*)d_in[0];
    const float* key   = (const float*)d_in[1];
    const float* value = (const float*)d_in[2];
    const int*   mask  = (const int*)d_in[3];
    const float* Wq    = (const float*)d_in[4];
    const float* bq    = (const float*)d_in[5];
    const float* Wk    = (const float*)d_in[6];
    const float* bk    = (const float*)d_in[7];
    const float* Wv    = (const float*)d_in[8];
    const float* bv    = (const float*)d_in[9];
    const float* Wo    = (const float*)d_in[10];

    u16* Qb   = (u16*)d_ws;                    // 1 MB
    u16* Kb   = Qb + (size_t)NA * HS;          // 1 MB
    u16* Vt   = Kb + (size_t)NA * HS;          // 1 MB
    u16* Wbuf = Vt + (size_t)NA * HS;          // 128 KB
    float* bb    = (float*)(Wbuf + 4 * 16384); // 1.5 KB
    float* partb = bb + 384;                   // 256*4*8*272 f32 = 8.9 MB

    cvt_w<<<64, 256, 0, stream>>>(Wq, Wk, Wv, Wo, bq, bk, bv, Wbuf, bb);
    proj_mfma<<<dim3(128, 3), 256, 0, stream>>>(query, key, value, Wbuf, bb, Qb, Kb, Vt);
    attn<<<dim3(256, 4), 512, 0, stream>>>(mask, Qb, Kb, Vt, partb);
    reduce_out<<<256, 256, 0, stream>>>(partb, Wbuf, (float*)d_out);
}

// Round 5
// 185.296 us; speedup vs baseline: 1.2284x; 1.2284x over previous
//
#include <hip/hip_runtime.h>

#define NA 4096
#define HS 128
#define PSTR 72    // attn P-buffer row stride (bf16 elems)
#define CSTR 136   // proj/reduce LDS row stride (bf16 elems)

typedef unsigned short u16;
typedef unsigned long long u64;
using bf16x8  = __attribute__((ext_vector_type(8))) short;
using f32x4   = __attribute__((ext_vector_type(4))) float;
using ushort8 = __attribute__((ext_vector_type(8))) unsigned short;

// 1/sqrt(dk)=0.25 * log2(e) * 0.5 (K-dim duplication in the 16x16x32 MFMA)
#define QSCALE 0.18033688011112042f

static __device__ __forceinline__ u16 f2bf(float f) {
    unsigned u = __builtin_bit_cast(unsigned, f);
    u += 0x7FFFu + ((u >> 16) & 1u);
    return (u16)(u >> 16);
}

// ---------------------------------------------------------------------------
// Kernel 0: weights -> bf16 in MFMA-fragment order:
//   Wf[mat][j0(8)][kk(4)][c(16)][q(4)][8]  (16384 elems per mat)
// so a proj B-fragment load (fixed j0,kk) is 1 KB contiguous across the wave.
// mat: 0=Q(x QSCALE), 1=K, 2=V, 3=O. bb[mat][j] f32 biases (bq pre-scaled).
// ---------------------------------------------------------------------------
__global__ __launch_bounds__(256) void cvt_w(
    const float* __restrict__ Wq, const float* __restrict__ Wk,
    const float* __restrict__ Wv, const float* __restrict__ Wo,
    const float* __restrict__ bq, const float* __restrict__ bk,
    const float* __restrict__ bv,
    u16* __restrict__ Wf, float* __restrict__ bb)
{
    const int gid = blockIdx.x * 256 + threadIdx.x;   // 16384 threads
    const int e = gid * 4;
    const int mat = e >> 14, off = e & 16383;
    const float* src = (mat == 0) ? Wq : (mat == 1) ? Wk : (mat == 2) ? Wv : Wo;
    const float s = (mat == 0) ? QSCALE : 1.0f;
    float4 v = *(const float4*)(src + off);
    ushort4 o;
    o.x = f2bf(v.x * s); o.y = f2bf(v.y * s);
    o.z = f2bf(v.z * s); o.w = f2bf(v.w * s);
    const int j = off >> 7, k0 = off & 127;
    const int j0 = j >> 4, c = j & 15, kk = k0 >> 5, q = (k0 >> 3) & 3;
    const int tgt = mat * 16384 + ((j0 * 4 + kk) * 16 + c) * 32 + q * 8 + (k0 & 7);
    *(ushort4*)(Wf + tgt) = o;
    if (gid < 128)      bb[gid] = bq[gid] * QSCALE;
    else if (gid < 256) bb[gid] = bk[gid - 128];
    else if (gid < 384) bb[gid] = bv[gid - 256];
}

// ---------------------------------------------------------------------------
// Kernel 1: Q/K/V projections via MFMA. Block = 256 thr (4 waves) = 32 rows.
// Outputs:
//   Qbh/Kbh [head][4096][16]  (head-major: attn fragment loads contiguous)
//   VtB     [kb(64)][dim(128)][key(64)]  (PV fragment loads contiguous)
// ---------------------------------------------------------------------------
__global__ __launch_bounds__(256) void proj_mfma(
    const float* __restrict__ Xq, const float* __restrict__ Xk, const float* __restrict__ Xv,
    const u16* __restrict__ Wf, const float* __restrict__ bb,
    u16* __restrict__ Qbh, u16* __restrict__ Kbh, u16* __restrict__ VtB)
{
    const int mat = blockIdx.y;
    const float* X = (mat == 0) ? Xq : (mat == 1) ? Xk : Xv;
    const u16* Wm = Wf + mat * 16384;
    const float* bm = bb + mat * 128;
    const int r0b = blockIdx.x * 32;

    __shared__ __align__(16) u16 Xs[32 * CSTR];
    __shared__ __align__(16) u16 Cs[32 * CSTR];

    const int t = threadIdx.x;

    // stage X coalesced: thread -> row t>>3, 16 cols at (t&7)*16
    {
        const int r = t >> 3, cb = (t & 7) * 16;
        const float* Xr = X + (size_t)(r0b + r) * HS + cb;
#pragma unroll
        for (int seg = 0; seg < 4; ++seg) {
            float4 f = *(const float4*)(Xr + seg * 4);
            ushort4 u;
            u.x = f2bf(f.x); u.y = f2bf(f.y); u.z = f2bf(f.z); u.w = f2bf(f.w);
            *(ushort4*)(Xs + r * CSTR + cb + seg * 4) = u;
        }
    }
    __syncthreads();

    const int wv = t >> 6, lane = t & 63;
    const int c = lane & 15, q = lane >> 4;
    const int rw = (wv & 1) * 16;        // wave row offset in block
    const int j0b = (wv >> 1) * 4;       // wave col group (4 j0 of 16 cols)

    bf16x8 af[4];
#pragma unroll
    for (int kk = 0; kk < 4; ++kk)
        af[kk] = *(const bf16x8*)(Xs + (rw + c) * CSTR + kk * 32 + q * 8);

    const f32x4 zero = {0.f, 0.f, 0.f, 0.f};
#pragma unroll
    for (int jj = 0; jj < 4; ++jj) {
        const int j0 = j0b + jj;
        f32x4 acc = zero;
#pragma unroll
        for (int kk = 0; kk < 4; ++kk) {
            bf16x8 bf = *(const bf16x8*)(Wm + (j0 * 4 + kk) * 512 + c * 32 + q * 8);
            acc = __builtin_amdgcn_mfma_f32_16x16x32_bf16(af[kk], bf, acc, 0, 0, 0);
        }
        const float bias = bm[j0 * 16 + c];
#pragma unroll
        for (int r = 0; r < 4; ++r)
            Cs[(rw + 4 * q + r) * CSTR + j0 * 16 + c] = f2bf(acc[r] + bias);
    }
    __syncthreads();

    if (mat < 2) {
        u16* dst = (mat == 0) ? Qbh : Kbh;
        const int h8 = t >> 5, r = t & 31;
        const u16* src = Cs + r * CSTR + h8 * 16;
        u16* dp = dst + (size_t)h8 * (NA * 16) + (size_t)(r0b + r) * 16;
        *(bf16x8*)(dp)     = *(const bf16x8*)(src);
        // (16 elems = 32 B per row; single bf16x8 covers 8, need second)
        *(bf16x8*)(dp + 8) = *(const bf16x8*)(src + 8);
    } else {
        const int d = t >> 1, s = t & 1;
        const int kb = r0b >> 6, ko = (r0b & 32) + s * 16;
        ushort8 v0, v1;
#pragma unroll
        for (int jj = 0; jj < 8; ++jj) v0[jj] = Cs[(s * 16 + jj) * CSTR + d];
#pragma unroll
        for (int jj = 0; jj < 8; ++jj) v1[jj] = Cs[(s * 16 + 8 + jj) * CSTR + d];
        u16* dp = VtB + (size_t)kb * 8192 + d * 64 + ko;
        *(ushort8*)(dp)     = v0;
        *(ushort8*)(dp + 8) = v1;
    }
}

// ---------------------------------------------------------------------------
// Kernel 2: attention partials. Grid (256 tiles, 4 key-splits), 512 thr =
// 8 waves, wave = one head. Mask ballot-packed into LDS bits (coalesced).
// S^T = K*Q^T (lane holds 4 consecutive keys). All hot global loads are
// contiguous thanks to head-major K/Q and block-major V. p = 2^S (no max
// subtraction), partials add across splits.
// part[tile][split][head][272] = { O 16x16 f32, l 16 f32 }.
// ---------------------------------------------------------------------------
__global__ __launch_bounds__(512, 8) void attn(
    const int* __restrict__ mask,
    const u16* __restrict__ Qbh, const u16* __restrict__ Kbh, const u16* __restrict__ VtB,
    float* __restrict__ part)
{
    __shared__ __align__(16) u16 Pbuf[8 * 16 * PSTR];
    __shared__ __align__(8)  u64 Mwp[16 * 17];   // [query][word], padded stride

    const int t = threadIdx.x;
    const int h = t >> 6;        // wave = head
    const int lane = t & 63;
    const int c = lane & 15;
    const int q = lane >> 4;
    const int tile = blockIdx.x, split = blockIdx.y;
    const int i0 = tile * 16;
    const int kt0 = split * 1024;

    // --- ballot-pack mask bits: 256 u64 words, wave h does words h*32..+31
#pragma unroll 4
    for (int rr = 0; rr < 32; ++rr) {
        const int idx = h * 32 + rr;
        const int row = idx >> 4, wc = idx & 15;
        const int v = mask[(size_t)(i0 + row) * NA + kt0 + wc * 64 + lane];
        u64 b = __ballot(v != 0);
        if (lane == 0) Mwp[row * 17 + wc] = b;
    }

    const u16* Qh = Qbh + (size_t)h * (NA * 16);
    const u16* Kh = Kbh + (size_t)h * (NA * 16);

    // Q B-fragment (K-halves duplicated; x2 folded into QSCALE); contiguous.
    const bf16x8 qf = *(const bf16x8*)(Qh + (size_t)(i0 + c) * 16 + (q & 1) * 8);

    __syncthreads();

    const f32x4 zero = {0.f, 0.f, 0.f, 0.f};
    f32x4 Oacc = zero;
    float lsum = 0.f;
    u16* Pw = Pbuf + h * 16 * PSTR;

#pragma unroll 1
    for (int it = 0; it < 16; ++it) {
        const int kt = kt0 + it * 64;
        const u16* Vb = VtB + (size_t)(kt >> 6) * 8192 + (h * 16 + c) * 64;

        // S^T = K Q^T: lane (c,q) reg r = S[query i0+c][key kt+16*t4+4q+r]
        f32x4 ST[4];
#pragma unroll
        for (int t4 = 0; t4 < 4; ++t4) {
            bf16x8 kf = *(const bf16x8*)(Kh + (size_t)(kt + t4 * 16 + c) * 16 + (q & 1) * 8);
            ST[t4] = __builtin_amdgcn_mfma_f32_16x16x32_bf16(kf, qf, zero, 0, 0, 0);
        }
        // V B-fragments (contiguous 1KB per load across the wave)
        bf16x8 vf0 = *(const bf16x8*)(Vb + q * 8);
        bf16x8 vf1 = *(const bf16x8*)(Vb + 32 + q * 8);

        // mask bits: bit(16*t4+r) after shift = key 16*t4+4q+r
        u64 w = Mwp[c * 17 + it] >> (4 * q);
        unsigned mlo = (unsigned)w, mhi = (unsigned)(w >> 32);

#pragma unroll
        for (int t4 = 0; t4 < 4; ++t4) {
            const unsigned mw = (t4 < 2) ? mlo : mhi;
            const int sh = (t4 & 1) * 16;
            float p0 = ((mw >> (sh + 0)) & 1) ? __builtin_amdgcn_exp2f(ST[t4][0]) : 0.f;
            float p1 = ((mw >> (sh + 1)) & 1) ? __builtin_amdgcn_exp2f(ST[t4][1]) : 0.f;
            float p2 = ((mw >> (sh + 2)) & 1) ? __builtin_amdgcn_exp2f(ST[t4][2]) : 0.f;
            float p3 = ((mw >> (sh + 3)) & 1) ? __builtin_amdgcn_exp2f(ST[t4][3]) : 0.f;
            lsum += (p0 + p1) + (p2 + p3);
            unsigned lo = ((__builtin_bit_cast(unsigned, p0) + 0x8000u) >> 16)
                        | ((__builtin_bit_cast(unsigned, p1) + 0x8000u) & 0xFFFF0000u);
            unsigned hi = ((__builtin_bit_cast(unsigned, p2) + 0x8000u) >> 16)
                        | ((__builtin_bit_cast(unsigned, p3) + 0x8000u) & 0xFFFF0000u);
            *(uint2*)(Pw + c * PSTR + t4 * 16 + 4 * q) = make_uint2(lo, hi);
        }
        __asm__ volatile("" ::: "memory");
        __builtin_amdgcn_s_waitcnt(0xC07F);  // per-wave LDS drain
        __asm__ volatile("" ::: "memory");

        // O += P @ V
        bf16x8 pf0 = *(const bf16x8*)(Pw + c * PSTR + q * 8);
        bf16x8 pf1 = *(const bf16x8*)(Pw + c * PSTR + 32 + q * 8);
        Oacc = __builtin_amdgcn_mfma_f32_16x16x32_bf16(pf0, vf0, Oacc, 0, 0, 0);
        Oacc = __builtin_amdgcn_mfma_f32_16x16x32_bf16(pf1, vf1, Oacc, 0, 0, 0);
    }

    // l[query c]: sum the 4 q-lanes
    lsum += __shfl_xor(lsum, 16, 64);
    lsum += __shfl_xor(lsum, 32, 64);

    float* base = part + (size_t)((tile * 4 + split) * 8 + h) * 272;
#pragma unroll
    for (int r = 0; r < 4; ++r)
        base[(4 * q + r) * 16 + c] = Oacc[r];
    if (q == 0) base[256 + c] = lsum;
}

// ---------------------------------------------------------------------------
// Kernel 3: combine 4 split partials, normalize, output projection via MFMA.
// ---------------------------------------------------------------------------
__global__ __launch_bounds__(256) void reduce_out(
    const float* __restrict__ part, const u16* __restrict__ Wf,
    float* __restrict__ out)
{
    __shared__ __align__(16) u16 xs[16 * CSTR];

    const int t = threadIdx.x;
    const int tile = blockIdx.x;
    const int i0 = tile * 16;
    const float* Pt = part + (size_t)tile * 4 * 8 * 272;

    {
        const int i = t >> 4, d = t & 15;
#pragma unroll
        for (int h = 0; h < 8; ++h) {
            float os = 0.f, ls = 0.f;
#pragma unroll
            for (int s = 0; s < 4; ++s) {
                const float* b = Pt + (size_t)(s * 8 + h) * 272;
                os += b[i * 16 + d];
                ls += b[256 + i];
            }
            xs[i * CSTR + h * 16 + d] = f2bf(os / ls);
        }
    }
    __syncthreads();

    const int wv = t >> 6, lane = t & 63;
    const int c = lane & 15, q = lane >> 4;
    const u16* WoB = Wf + 3 * 16384;

    bf16x8 af[4];
#pragma unroll
    for (int kk = 0; kk < 4; ++kk)
        af[kk] = *(const bf16x8*)(xs + c * CSTR + kk * 32 + q * 8);

    const f32x4 zero = {0.f, 0.f, 0.f, 0.f};
#pragma unroll
    for (int jj = 0; jj < 2; ++jj) {
        const int j0 = wv * 2 + jj;
        f32x4 acc = zero;
#pragma unroll
        for (int kk = 0; kk < 4; ++kk) {
            bf16x8 bf = *(const bf16x8*)(WoB + (j0 * 4 + kk) * 512 + c * 32 + q * 8);
            acc = __builtin_amdgcn_mfma_f32_16x16x32_bf16(af[kk], bf, acc, 0, 0, 0);
        }
#pragma unroll
        for (int r = 0; r < 4; ++r)
            out[(size_t)(i0 + 4 * q + r) * HS + j0 * 16 + c] = acc[r];
    }
}

extern "C" void kernel_launch(void* const* d_in, const int* in_sizes, int n_in,
                              void* d_out, int out_size, void* d_ws, size_t ws_size,
                              hipStream_t stream) {
    const float* query = (const float*)d_in[0];
    const float* key   = (const float*)d_in[1];
    const float* value = (const float*)d_in[2];
    const int*   mask  = (const int*)d_in[3];
    const float* Wq    = (const float*)d_in[4];
    const float* bq    = (const float*)d_in[5];
    const float* Wk    = (const float*)d_in[6];
    const float* bk    = (const float*)d_in[7];
    const float* Wv    = (const float*)d_in[8];
    const float* bv    = (const float*)d_in[9];
    const float* Wo    = (const float*)d_in[10];

    u16* Qbh = (u16*)d_ws;                     // 1 MB  [8][4096][16]
    u16* Kbh = Qbh + (size_t)NA * HS;          // 1 MB  [8][4096][16]
    u16* VtB = Kbh + (size_t)NA * HS;          // 1 MB  [64][128][64]
    u16* Wf  = VtB + (size_t)NA * HS;          // 128 KB
    float* bb    = (float*)(Wf + 4 * 16384);   // 1.5 KB
    float* partb = bb + 384;                   // 256*4*8*272 f32 = 8.9 MB

    cvt_w<<<64, 256, 0, stream>>>(Wq, Wk, Wv, Wo, bq, bk, bv, Wf, bb);
    proj_mfma<<<dim3(128, 3), 256, 0, stream>>>(query, key, value, Wf, bb, Qbh, Kbh, VtB);
    attn<<<dim3(256, 4), 512, 0, stream>>>(mask, Qbh, Kbh, VtB, partb);
    reduce_out<<<256, 256, 0, stream>>>(partb, Wf, (float*)d_out);
}